// Round 20
// baseline (47.701 us; speedup 1.0000x reference)
//
#include <hip/hip_runtime.h>
#include <hip/hip_bf16.h>

#define LB 2048
#define DB 256
#define HB 8
#define BH 32     // B*H
#define NG 19     // prior nodes: node g at i = 128*(g-1)
#define NROW 48   // A rows: 0-18 P, 19-37 P*d, 38-47 zero
#define NCK 16    // conv K-chunks (128 m each)

typedef __attribute__((ext_vector_type(8))) short short8;
typedef __attribute__((ext_vector_type(4))) short short4v;
typedef __attribute__((ext_vector_type(4))) float floatx4;

static __device__ __forceinline__ short bfbits(float f) {
    __hip_bfloat16 h = __float2bfloat16(f);
    return *reinterpret_cast<short*>(&h);
}

// ---------------- prep_all: x fragments (0-511) + W fragments (512-575) + prior A (576-671)
// (R17-verified verbatim)
__global__ __launch_bounds__(256) void prep_all(
    const float* __restrict__ x, const float* __restrict__ Wq,
    const float* __restrict__ Wk, const float* __restrict__ pm,
    const float* __restrict__ ls,
    __hip_bfloat16* __restrict__ xb, __hip_bfloat16* __restrict__ wb,
    __hip_bfloat16* __restrict__ prtF)
{
    if (blockIdx.x < 512) {
        const int t   = blockIdx.x;
        const int ksg = threadIdx.x & 31;
#pragma unroll
        for (int p = 0; p < 2; ++p) {
            const int l = (threadIdx.x >> 5) + 8 * p;
            const float* src = x + (size_t)(t * 16 + l) * DB + ksg * 8;
            const float4 v0 = *reinterpret_cast<const float4*>(src);
            const float4 v1 = *reinterpret_cast<const float4*>(src + 4);
            short8 o;
            o[0] = bfbits(v0.x); o[1] = bfbits(v0.y); o[2] = bfbits(v0.z); o[3] = bfbits(v0.w);
            o[4] = bfbits(v1.x); o[5] = bfbits(v1.y); o[6] = bfbits(v1.z); o[7] = bfbits(v1.w);
            *(reinterpret_cast<short8*>(xb + (size_t)t * 4096) + (ksg * 16 + l)) = o;
        }
        return;
    }
    if (blockIdx.x < 576) {
        const int blk = blockIdx.x - 512;         // 0..63
        const float* W = (blk & 32) ? Wk : Wq;
        const int nbase = (blk & 31) * 16;
#pragma unroll
        for (int cc = 0; cc < 2; ++cc) {
            const int c  = threadIdx.x + cc * 256;
            const int n  = nbase + (c & 15);
            const int k0 = (c >> 4) * 8;
            short8 o;
#pragma unroll
            for (int e = 0; e < 8; ++e) o[e] = bfbits(W[(size_t)(k0 + e) * 512 + n]);
            *(reinterpret_cast<short8*>(wb + (size_t)blk * 4096) + c) = o;
        }
        return;
    }
    // prior A-fragments
    const int blk2 = blockIdx.x - 576;            // 0..95
    const int h    = blk2 / 12;
    const int rem  = blk2 - h * 12;
    const int gt   = rem >> 2;
    const int msq  = rem & 3;
    const int wv   = threadIdx.x >> 6;
    const int l    = threadIdx.x & 63;

    const float mu        = pm[h];
    const float inv_sigma = __expf(-ls[h]);
    const float coef = 0.125f * inv_sigma * (1.0f / 2.5066282f);

    const int row = gt * 16 + (l & 15);           // A row 0..47
#pragma unroll
    for (int it = 0; it < 4; ++it) {
        const int ms = msq * 16 + wv * 4 + it;    // 0..63
        const int m0 = ms * 32 + (l >> 4) * 8;
        short8 o;
#pragma unroll
        for (int e = 0; e < 8; ++e) {
            float val = 0.f;
            if (row < 38) {
                const int g = (row < 19) ? row : row - 19;
                const float d = (float)(m0 + e - 128 * g + 128);
                const float t = (d - mu) * inv_sigma;
                const float P = coef * __expf(-0.5f * t * t);
                val = (row < 19) ? P : P * d;
            }
            o[e] = bfbits(val);
        }
        reinterpret_cast<short8*>(prtF)[(size_t)((h * 3 + gt) * 64 + ms) * 64 + l] = o;
    }
}

// ---------------- proj: A-fragments from global xb; q -> row-major, k -> kT (R17-identical)
__global__ __launch_bounds__(256) void proj_mfma(
    const __hip_bfloat16* __restrict__ xb, const __hip_bfloat16* __restrict__ wb,
    const float* __restrict__ bq, const float* __restrict__ bk,
    __hip_bfloat16* __restrict__ qf, __hip_bfloat16* __restrict__ kT)
{
    __shared__ __align__(16) __hip_bfloat16 ot[64][136];

    const int rt   = blockIdx.x;              // 64-row block
    const int cg   = blockIdx.y;              // 0-3: q, 4-7: k
    const int wave = threadIdx.x >> 6;
    const int lane = threadIdx.x & 63;
    const int kg   = lane >> 4;
    const int l15  = lane & 15;

    const short8* xp = reinterpret_cast<const short8*>(xb)
                     + (size_t)(rt * 4 + wave) * 512 + lane;
    short8 a[8];
#pragma unroll
    for (int kb = 0; kb < 8; ++kb) a[kb] = xp[kb * 64];

    const int b_   = rt >> 5;
    const int gct0 = cg * 8;
    const short8* wp = reinterpret_cast<const short8*>(wb) + lane;

    short8 wA[8], wB[8];
#pragma unroll
    for (int kb = 0; kb < 8; ++kb) wA[kb] = wp[(size_t)(gct0 * 8 + kb) * 64];

#define PROJ_STEP(CURW, NXTW, CT)                                                     \
    {                                                                                 \
        if ((CT) < 7) {                                                               \
            _Pragma("unroll")                                                         \
            for (int kb = 0; kb < 8; ++kb)                                            \
                NXTW[kb] = wp[(size_t)((gct0 + (CT) + 1) * 8 + kb) * 64];             \
        }                                                                             \
        floatx4 acc = {0.f, 0.f, 0.f, 0.f};                                           \
        _Pragma("unroll")                                                             \
        for (int kb = 0; kb < 8; ++kb)                                                \
            acc = __builtin_amdgcn_mfma_f32_16x16x32_bf16(CURW[kb], a[kb], acc, 0, 0, 0); \
        const int h   = ((gct0 + (CT)) & 31) >> 2;                                    \
        const float bias = (cg < 4 ? bq : bk)[h];                                     \
        short4v o;                                                                    \
        _Pragma("unroll")                                                             \
        for (int r = 0; r < 4; ++r) o[r] = bfbits(acc[r] + bias);                     \
        *reinterpret_cast<short4v*>(&ot[wave * 16 + l15][(CT) * 16 + 4 * kg]) = o;    \
    }

    PROJ_STEP(wA, wB, 0)
    PROJ_STEP(wB, wA, 1)
    PROJ_STEP(wA, wB, 2)
    PROJ_STEP(wB, wA, 3)
    PROJ_STEP(wA, wB, 4)
    PROJ_STEP(wB, wA, 5)
    PROJ_STEP(wA, wB, 6)
    PROJ_STEP(wB, wA, 7)
#undef PROJ_STEP

    __syncthreads();

    if (cg < 4) {
        const int h0 = (cg & 3) * 2;
        const int rbase = (rt & 31) * 64;
#pragma unroll
        for (int it = 0; it < 8; ++it) {
            const int cidx = threadIdx.x + it * 256;
            const int row  = cidx >> 5;
            const int sub  = cidx & 31;
            const int hoff = sub >> 4;
            const int ch64 = (sub & 15) * 4;
            const short4v v = *reinterpret_cast<const short4v*>(&ot[row][sub * 4]);
            const size_t dst = (((size_t)(b_ * HB + h0 + hoff) << 11) + rbase + row) * 64 + ch64;
            *reinterpret_cast<short4v*>(qf + dst) = v;
        }
    } else {
        const int hoff = wave >> 1;
        const int msb  = wave & 1;
        const int h0   = (cg & 3) * 2;
        const int bh   = b_ * HB + h0 + hoff;
        const int msG  = (rt & 31) * 2 + msb;
        const int rowb = msb * 32 + (lane >> 4) * 8;
        const int colb = hoff * 64 + l15;
#pragma unroll
        for (int ct = 0; ct < 4; ++ct) {
            short8 o;
#pragma unroll
            for (int e = 0; e < 8; ++e)
                o[e] = *reinterpret_cast<const short*>(&ot[rowb + e][colb + ct * 16]);
            reinterpret_cast<short8*>(kT)[(size_t)((bh * 4 + ct) * 64 + msG) * 64 + lane] = o;
        }
    }
}

// ---------------- conv_final: per (bh, oct) block — full G[48x64] via MFMA (redundant
// 8x, negligible), LDS reduce, then final interp for this oct's 256 rows. No globals
// between conv and final; no atomics; grid 256.
__global__ __launch_bounds__(256) void conv_final(
    const __hip_bfloat16* __restrict__ prtF, const __hip_bfloat16* __restrict__ kT,
    const __hip_bfloat16* __restrict__ qf, float* __restrict__ out)
{
    __shared__ float red[4][3072];    // 48 KB: per-wave G partials, then red[0] = G

    const int bh   = blockIdx.x;      // 0..31
    const int oct  = blockIdx.y;      // 0..7
    const int tid  = threadIdx.x;
    const int wv   = tid >> 6;
    const int lane = tid & 63;
    const int h    = bh & 7;
    const int b    = bh >> 3;
    const int kg   = lane >> 4;
    const int l15w = lane & 15;

    // ---- phase 1: conv (R18-verified conv_fused loop: 4 chunks/wave x 4 steps)
    {
        const short8* A = reinterpret_cast<const short8*>(prtF);
        const short8* B = reinterpret_cast<const short8*>(kT);

        floatx4 acc[3][4];
#pragma unroll
        for (int gt = 0; gt < 3; ++gt)
#pragma unroll
            for (int ct = 0; ct < 4; ++ct) acc[gt][ct] = (floatx4){0.f, 0.f, 0.f, 0.f};

#pragma unroll
        for (int cki = 0; cki < 4; ++cki) {
            const int ck = wv * 4 + cki;
#pragma unroll
            for (int s = 0; s < 4; ++s) {
                const int ms = ck * 4 + s;
                short8 af[3], bf[4];
#pragma unroll
                for (int gt = 0; gt < 3; ++gt)
                    af[gt] = A[(size_t)((h * 3 + gt) * 64 + ms) * 64 + lane];
#pragma unroll
                for (int ct = 0; ct < 4; ++ct)
                    bf[ct] = B[(size_t)((bh * 4 + ct) * 64 + ms) * 64 + lane];
#pragma unroll
                for (int gt = 0; gt < 3; ++gt)
#pragma unroll
                    for (int ct = 0; ct < 4; ++ct)
                        acc[gt][ct] = __builtin_amdgcn_mfma_f32_16x16x32_bf16(af[gt], bf[ct], acc[gt][ct], 0, 0, 0);
            }
        }

#pragma unroll
        for (int gt = 0; gt < 3; ++gt)
#pragma unroll
            for (int ct = 0; ct < 4; ++ct)
#pragma unroll
                for (int r = 0; r < 4; ++r)
                    red[wv][(gt * 16 + 4 * kg + r) * 64 + ct * 16 + l15w] = acc[gt][ct][r];
    }
    __syncthreads();

    // reduce 4 slabs into red[0]
    for (int j = tid; j < 3072; j += 256)
        red[0][j] = red[0][j] + red[1][j] + red[2][j] + red[3][j];
    __syncthreads();

    // ---- phase 2: final for rows [oct*256, oct*256+256) (R17-verified math, taps from LDS)
    const int l15 = tid & 15;
    const float4* g4 = reinterpret_cast<const float4*>(&red[0][0]) + l15;

#pragma unroll 2
    for (int it = 0; it < 16; ++it) {
        const int i = oct * 256 + it * 16 + (tid >> 4);   // row within [L]
        const size_t grow = ((size_t)bh << 11) + i;

        const short4v q4 = reinterpret_cast<const short4v*>(qf)[grow * 16 + l15];
        float q[4];
#pragma unroll
        for (int e = 0; e < 4; ++e) {
            const unsigned short u16 = (unsigned short)q4[e];
            const unsigned int bits = ((unsigned int)u16) << 16;
            q[e] = __builtin_bit_cast(float, bits);
        }

        const int   cell = i >> 7;
        const float u  = (float)(i & 127) * (1.0f / 128.0f);
        const float u2 = u * u, u3 = u2 * u;
        const float c0 = -0.5f * u + u2 - 0.5f * u3;
        const float c1 = 1.0f - 2.5f * u2 + 1.5f * u3;
        const float c2 = 0.5f * u + 2.0f * u2 - 1.5f * u3;
        const float c3 = -0.5f * u2 + 0.5f * u3;

        const float4 n0 = g4[(cell + 0) * 16], n1 = g4[(cell + 1) * 16];
        const float4 n2 = g4[(cell + 2) * 16], n3 = g4[(cell + 3) * 16];
        const float4 w0 = g4[(19 + cell + 0) * 16], w1 = g4[(19 + cell + 1) * 16];
        const float4 w2 = g4[(19 + cell + 2) * 16], w3 = g4[(19 + cell + 3) * 16];

        float D = q[0] * (c0 * n0.x + c1 * n1.x + c2 * n2.x + c3 * n3.x)
                + q[1] * (c0 * n0.y + c1 * n1.y + c2 * n2.y + c3 * n3.y)
                + q[2] * (c0 * n0.z + c1 * n1.z + c2 * n2.z + c3 * n3.z)
                + q[3] * (c0 * n0.w + c1 * n1.w + c2 * n2.w + c3 * n3.w);
        float N = q[0] * (c0 * w0.x + c1 * w1.x + c2 * w2.x + c3 * w3.x)
                + q[1] * (c0 * w0.y + c1 * w1.y + c2 * w2.y + c3 * w3.y)
                + q[2] * (c0 * w0.z + c1 * w1.z + c2 * w2.z + c3 * w3.z)
                + q[3] * (c0 * w0.w + c1 * w1.w + c2 * w2.w + c3 * w3.w);

#pragma unroll
        for (int off = 8; off >= 1; off >>= 1) {
            D += __shfl_xor(D, off, 64);
            N += __shfl_xor(N, off, 64);
        }
        if (l15 == 0) {
            const float C = (float)(2096128 - 2048 * i);   // sum_m (m - i), exact
            out[((size_t)(b * LB + i)) * HB + h] = (C + N) / (2048.0f + D);
        }
    }
}

extern "C" void kernel_launch(void* const* d_in, const int* in_sizes, int n_in,
                              void* d_out, int out_size, void* d_ws, size_t ws_size,
                              hipStream_t stream) {
    const float* x  = (const float*)d_in[0];
    const float* Wq = (const float*)d_in[1];
    const float* bq = (const float*)d_in[2];
    const float* Wk = (const float*)d_in[3];
    const float* bk = (const float*)d_in[4];
    const float* pm = (const float*)d_in[5];
    const float* ls = (const float*)d_in[6];
    float* out = (float*)d_out;

    char* w = (char*)d_ws;
    __hip_bfloat16* xb   = (__hip_bfloat16*)w;  w += (size_t)512 * 4096 * 2;            // 4.2 MB
    __hip_bfloat16* wbuf = (__hip_bfloat16*)w;  w += (size_t)64 * 4096 * 2;             // 0.5 MB
    __hip_bfloat16* prtF = (__hip_bfloat16*)w;  w += (size_t)24 * 64 * 64 * 8 * 2;      // 1.6 MB
    __hip_bfloat16* qf   = (__hip_bfloat16*)w;  w += (size_t)BH * LB * 64 * 2;          // 8.4 MB
    __hip_bfloat16* kT   = (__hip_bfloat16*)w;                                           // 8.4 MB

    prep_all<<<dim3(672), dim3(256), 0, stream>>>(x, Wq, Wk, pm, ls, xb, wbuf, prtF);
    proj_mfma<<<dim3(128, 8), dim3(256), 0, stream>>>(xb, wbuf, bq, bk, qf, kT);
    conv_final<<<dim3(32, 8), dim3(256), 0, stream>>>(prtF, kT, qf, out);
}

// Round 21
// 39.817 us; speedup vs baseline: 1.1980x; 1.1980x over previous
//
#include <hip/hip_runtime.h>
#include <hip/hip_bf16.h>

#define LB 2048
#define DB 256
#define HB 8
#define BH 32     // B*H
#define NG 19     // prior nodes: node g at i = 128*(g-1)
#define NROW 48   // A rows: 0-18 P, 19-37 P*d, 38-47 zero
#define NCK 16    // conv K-chunks (128 m each)

typedef __attribute__((ext_vector_type(8))) short short8;
typedef __attribute__((ext_vector_type(4))) short short4v;
typedef __attribute__((ext_vector_type(4))) float floatx4;

static __device__ __forceinline__ short bfbits(float f) {
    __hip_bfloat16 h = __float2bfloat16(f);
    return *reinterpret_cast<short*>(&h);
}

// ---------------- prep_all: x fragments (0-511) + W fragments (512-575) + prior A (576-671)
__global__ __launch_bounds__(256) void prep_all(
    const float* __restrict__ x, const float* __restrict__ Wq,
    const float* __restrict__ Wk, const float* __restrict__ pm,
    const float* __restrict__ ls,
    __hip_bfloat16* __restrict__ xb, __hip_bfloat16* __restrict__ wb,
    __hip_bfloat16* __restrict__ prtF)
{
    if (blockIdx.x < 512) {
        // x fp32 [8192][256] -> bf16 fragment tiles [512][4096] (coalesced)
        const int t   = blockIdx.x;
        const int ksg = threadIdx.x & 31;
#pragma unroll
        for (int p = 0; p < 2; ++p) {
            const int l = (threadIdx.x >> 5) + 8 * p;
            const float* src = x + (size_t)(t * 16 + l) * DB + ksg * 8;
            const float4 v0 = *reinterpret_cast<const float4*>(src);
            const float4 v1 = *reinterpret_cast<const float4*>(src + 4);
            short8 o;
            o[0] = bfbits(v0.x); o[1] = bfbits(v0.y); o[2] = bfbits(v0.z); o[3] = bfbits(v0.w);
            o[4] = bfbits(v1.x); o[5] = bfbits(v1.y); o[6] = bfbits(v1.z); o[7] = bfbits(v1.w);
            *(reinterpret_cast<short8*>(xb + (size_t)t * 4096) + (ksg * 16 + l)) = o;
        }
        return;
    }
    if (blockIdx.x < 576) {
        // W [256][512] -> transposed bf16 fragment tiles
        const int blk = blockIdx.x - 512;         // 0..63
        const float* W = (blk & 32) ? Wk : Wq;
        const int nbase = (blk & 31) * 16;
#pragma unroll
        for (int cc = 0; cc < 2; ++cc) {
            const int c  = threadIdx.x + cc * 256;
            const int n  = nbase + (c & 15);
            const int k0 = (c >> 4) * 8;
            short8 o;
#pragma unroll
            for (int e = 0; e < 8; ++e) o[e] = bfbits(W[(size_t)(k0 + e) * 512 + n]);
            *(reinterpret_cast<short8*>(wb + (size_t)blk * 4096) + c) = o;
        }
        return;
    }
    // prior A-fragments: blk2 = (h, gt, ms-quarter)
    const int blk2 = blockIdx.x - 576;            // 0..95
    const int h    = blk2 / 12;
    const int rem  = blk2 - h * 12;
    const int gt   = rem >> 2;
    const int msq  = rem & 3;
    const int wv   = threadIdx.x >> 6;
    const int l    = threadIdx.x & 63;

    const float mu        = pm[h];
    const float inv_sigma = __expf(-ls[h]);
    const float coef = 0.125f * inv_sigma * (1.0f / 2.5066282f);

    const int row = gt * 16 + (l & 15);           // A row 0..47
#pragma unroll
    for (int it = 0; it < 4; ++it) {
        const int ms = msq * 16 + wv * 4 + it;    // 0..63
        const int m0 = ms * 32 + (l >> 4) * 8;
        short8 o;
#pragma unroll
        for (int e = 0; e < 8; ++e) {
            float val = 0.f;
            if (row < 38) {
                const int g = (row < 19) ? row : row - 19;
                const float d = (float)(m0 + e - 128 * g + 128);
                const float t = (d - mu) * inv_sigma;
                const float P = coef * __expf(-0.5f * t * t);
                val = (row < 19) ? P : P * d;
            }
            o[e] = bfbits(val);
        }
        reinterpret_cast<short8*>(prtF)[(size_t)((h * 3 + gt) * 64 + ms) * 64 + l] = o;
    }
}

// ---------------- proj: A-fragments from global xb (coalesced); q -> row-major, k -> kT
__global__ __launch_bounds__(256) void proj_mfma(
    const __hip_bfloat16* __restrict__ xb, const __hip_bfloat16* __restrict__ wb,
    const float* __restrict__ bq, const float* __restrict__ bk,
    __hip_bfloat16* __restrict__ qf, __hip_bfloat16* __restrict__ kT)
{
    __shared__ __align__(16) __hip_bfloat16 ot[64][136];   // 17.4 KB transpose buffer

    const int rt   = blockIdx.x;              // 64-row block
    const int cg   = blockIdx.y;              // 0-3: q, 4-7: k
    const int wave = threadIdx.x >> 6;
    const int lane = threadIdx.x & 63;
    const int kg   = lane >> 4;
    const int l15  = lane & 15;

    // x fragments straight from global (16B/lane, layout proven R4-R13)
    const short8* xp = reinterpret_cast<const short8*>(xb)
                     + (size_t)(rt * 4 + wave) * 512 + lane;
    short8 a[8];
#pragma unroll
    for (int kb = 0; kb < 8; ++kb) a[kb] = xp[kb * 64];

    const int b_   = rt >> 5;
    const int gct0 = cg * 8;
    const short8* wp = reinterpret_cast<const short8*>(wb) + lane;

    short8 wA[8], wB[8];
#pragma unroll
    for (int kb = 0; kb < 8; ++kb) wA[kb] = wp[(size_t)(gct0 * 8 + kb) * 64];

#define PROJ_STEP(CURW, NXTW, CT)                                                     \
    {                                                                                 \
        if ((CT) < 7) {                                                               \
            _Pragma("unroll")                                                         \
            for (int kb = 0; kb < 8; ++kb)                                            \
                NXTW[kb] = wp[(size_t)((gct0 + (CT) + 1) * 8 + kb) * 64];             \
        }                                                                             \
        floatx4 acc = {0.f, 0.f, 0.f, 0.f};                                           \
        _Pragma("unroll")                                                             \
        for (int kb = 0; kb < 8; ++kb)                                                \
            acc = __builtin_amdgcn_mfma_f32_16x16x32_bf16(CURW[kb], a[kb], acc, 0, 0, 0); \
        const int h   = ((gct0 + (CT)) & 31) >> 2;                                    \
        const float bias = (cg < 4 ? bq : bk)[h];                                     \
        short4v o;                                                                    \
        _Pragma("unroll")                                                             \
        for (int r = 0; r < 4; ++r) o[r] = bfbits(acc[r] + bias);                     \
        *reinterpret_cast<short4v*>(&ot[wave * 16 + l15][(CT) * 16 + 4 * kg]) = o;    \
    }

    PROJ_STEP(wA, wB, 0)
    PROJ_STEP(wB, wA, 1)
    PROJ_STEP(wA, wB, 2)
    PROJ_STEP(wB, wA, 3)
    PROJ_STEP(wA, wB, 4)
    PROJ_STEP(wB, wA, 5)
    PROJ_STEP(wA, wB, 6)
    PROJ_STEP(wB, wA, 7)
#undef PROJ_STEP

    __syncthreads();

    if (cg < 4) {
        // q: coalesced row-major copy-out (verified R15/R16)
        const int h0 = (cg & 3) * 2;
        const int rbase = (rt & 31) * 64;
#pragma unroll
        for (int it = 0; it < 8; ++it) {
            const int cidx = threadIdx.x + it * 256;
            const int row  = cidx >> 5;
            const int sub  = cidx & 31;
            const int hoff = sub >> 4;
            const int ch64 = (sub & 15) * 4;
            const short4v v = *reinterpret_cast<const short4v*>(&ot[row][sub * 4]);
            const size_t dst = (((size_t)(b_ * HB + h0 + hoff) << 11) + rbase + row) * 64 + ch64;
            *reinterpret_cast<short4v*>(qf + dst) = v;
        }
    } else {
        // k: emit kT B-fragments (verified R16)
        const int hoff = wave >> 1;
        const int msb  = wave & 1;
        const int h0   = (cg & 3) * 2;
        const int bh   = b_ * HB + h0 + hoff;
        const int msG  = (rt & 31) * 2 + msb;
        const int rowb = msb * 32 + (lane >> 4) * 8;
        const int colb = hoff * 64 + l15;
#pragma unroll
        for (int ct = 0; ct < 4; ++ct) {
            short8 o;
#pragma unroll
            for (int e = 0; e < 8; ++e)
                o[e] = *reinterpret_cast<const short*>(&ot[rowb + e][colb + ct * 16]);
            reinterpret_cast<short8*>(kT)[(size_t)((bh * 4 + ct) * 64 + msG) * 64 + lane] = o;
        }
    }
}

// ---------------- conv via MFMA: G[48 x 64] = prior[48 x 2048] . kT (unchanged R16)
__global__ __launch_bounds__(256, 2) void conv_mfma(
    const __hip_bfloat16* __restrict__ prtF, const __hip_bfloat16* __restrict__ kT,
    float* __restrict__ gpart)
{
    const int bh   = blockIdx.x;
    const int wv   = threadIdx.x >> 6;
    const int lane = threadIdx.x & 63;
    const int ck   = blockIdx.y * 4 + wv;     // 0..15
    const int h    = bh & 7;

    const short8* A = reinterpret_cast<const short8*>(prtF);
    const short8* B = reinterpret_cast<const short8*>(kT);

    floatx4 acc[3][4];
#pragma unroll
    for (int gt = 0; gt < 3; ++gt)
#pragma unroll
        for (int ct = 0; ct < 4; ++ct) acc[gt][ct] = (floatx4){0.f, 0.f, 0.f, 0.f};

#pragma unroll
    for (int s = 0; s < 4; ++s) {
        const int ms = ck * 4 + s;
        short8 af[3], bf[4];
#pragma unroll
        for (int gt = 0; gt < 3; ++gt)
            af[gt] = A[(size_t)((h * 3 + gt) * 64 + ms) * 64 + lane];
#pragma unroll
        for (int ct = 0; ct < 4; ++ct)
            bf[ct] = B[(size_t)((bh * 4 + ct) * 64 + ms) * 64 + lane];
#pragma unroll
        for (int gt = 0; gt < 3; ++gt)
#pragma unroll
            for (int ct = 0; ct < 4; ++ct)
                acc[gt][ct] = __builtin_amdgcn_mfma_f32_16x16x32_bf16(af[gt], bf[ct], acc[gt][ct], 0, 0, 0);
    }

    const int kg = lane >> 4, l15 = lane & 15;
    float* gp = gpart + (size_t)(bh * NCK + ck) * (NROW * 64);
#pragma unroll
    for (int gt = 0; gt < 3; ++gt)
#pragma unroll
        for (int ct = 0; ct < 4; ++ct)
#pragma unroll
            for (int r = 0; r < 4; ++r)
                gp[(gt * 16 + 4 * kg + r) * 64 + ct * 16 + l15] = acc[gt][ct][r];
}

// ---------------- combine 16 K-chunks: gw[bh][48][64] (unchanged R16)
__global__ __launch_bounds__(256) void conv_combine(const float* __restrict__ gpart,
                                                    float* __restrict__ gw)
{
    const int j   = blockIdx.x * 256 + threadIdx.x;   // 0..98303 (grid exact)
    const int bh  = j / 3072;
    const int idx = j - bh * 3072;
    const float* gp = gpart + (size_t)bh * NCK * 3072 + idx;
    float s = 0.f;
#pragma unroll
    for (int c = 0; c < NCK; ++c) s += gp[(size_t)c * 3072];
    gw[j] = s;
}

// ---------------- final: Catmull-Rom interp + q-dot (unchanged R16)
__global__ __launch_bounds__(256) void final_kernel(
    const __hip_bfloat16* __restrict__ qf, const float* __restrict__ gw,
    float* __restrict__ out)
{
    const int row = blockIdx.x * 16 + (threadIdx.x >> 4);  // bh*2048 + i
    const int l15 = threadIdx.x & 15;
    const int bh  = row >> 11;
    const int i   = row & (LB - 1);
    const int b   = bh >> 3;
    const int h   = bh & 7;

    const short4v q4 = reinterpret_cast<const short4v*>(qf)[(size_t)row * 16 + l15];
    float q[4];
#pragma unroll
    for (int e = 0; e < 4; ++e) {
        const unsigned short u16 = (unsigned short)q4[e];
        const unsigned int bits = ((unsigned int)u16) << 16;
        q[e] = __builtin_bit_cast(float, bits);
    }

    const int   cell = i >> 7;
    const float u  = (float)(i & 127) * (1.0f / 128.0f);
    const float u2 = u * u, u3 = u2 * u;
    const float c0 = -0.5f * u + u2 - 0.5f * u3;
    const float c1 = 1.0f - 2.5f * u2 + 1.5f * u3;
    const float c2 = 0.5f * u + 2.0f * u2 - 1.5f * u3;
    const float c3 = -0.5f * u2 + 0.5f * u3;

    const float4* g4 = reinterpret_cast<const float4*>(gw + (size_t)bh * 3072) + l15;
    const float4 n0 = g4[(cell + 0) * 16], n1 = g4[(cell + 1) * 16];
    const float4 n2 = g4[(cell + 2) * 16], n3 = g4[(cell + 3) * 16];
    const float4 w0 = g4[(19 + cell + 0) * 16], w1 = g4[(19 + cell + 1) * 16];
    const float4 w2 = g4[(19 + cell + 2) * 16], w3 = g4[(19 + cell + 3) * 16];

    float D = q[0] * (c0 * n0.x + c1 * n1.x + c2 * n2.x + c3 * n3.x)
            + q[1] * (c0 * n0.y + c1 * n1.y + c2 * n2.y + c3 * n3.y)
            + q[2] * (c0 * n0.z + c1 * n1.z + c2 * n2.z + c3 * n3.z)
            + q[3] * (c0 * n0.w + c1 * n1.w + c2 * n2.w + c3 * n3.w);
    float N = q[0] * (c0 * w0.x + c1 * w1.x + c2 * w2.x + c3 * w3.x)
            + q[1] * (c0 * w0.y + c1 * w1.y + c2 * w2.y + c3 * w3.y)
            + q[2] * (c0 * w0.z + c1 * w1.z + c2 * w2.z + c3 * w3.z)
            + q[3] * (c0 * w0.w + c1 * w1.w + c2 * w2.w + c3 * w3.w);

#pragma unroll
    for (int off = 8; off >= 1; off >>= 1) {
        D += __shfl_xor(D, off, 64);
        N += __shfl_xor(N, off, 64);
    }
    if (l15 == 0) {
        const float C = (float)(2096128 - 2048 * i);   // sum_m (m - i), exact
        out[((size_t)(b * LB + i)) * HB + h] = (C + N) / (2048.0f + D);
    }
}

extern "C" void kernel_launch(void* const* d_in, const int* in_sizes, int n_in,
                              void* d_out, int out_size, void* d_ws, size_t ws_size,
                              hipStream_t stream) {
    const float* x  = (const float*)d_in[0];
    const float* Wq = (const float*)d_in[1];
    const float* bq = (const float*)d_in[2];
    const float* Wk = (const float*)d_in[3];
    const float* bk = (const float*)d_in[4];
    const float* pm = (const float*)d_in[5];
    const float* ls = (const float*)d_in[6];
    float* out = (float*)d_out;

    char* w = (char*)d_ws;
    __hip_bfloat16* xb   = (__hip_bfloat16*)w;  w += (size_t)512 * 4096 * 2;            // 4.2 MB
    __hip_bfloat16* wbuf = (__hip_bfloat16*)w;  w += (size_t)64 * 4096 * 2;             // 0.5 MB
    __hip_bfloat16* prtF = (__hip_bfloat16*)w;  w += (size_t)24 * 64 * 64 * 8 * 2;      // 1.6 MB
    __hip_bfloat16* qf   = (__hip_bfloat16*)w;  w += (size_t)BH * LB * 64 * 2;          // 8.4 MB
    __hip_bfloat16* kT   = (__hip_bfloat16*)w;  w += (size_t)BH * 4 * 64 * 64 * 8 * 2;  // 8.4 MB
    float*          gpart = (float*)w;          w += (size_t)BH * NCK * NROW * 64 * 4;  // 6.3 MB
    float*          gw    = (float*)w;                                                  // 0.4 MB

    prep_all<<<dim3(672), dim3(256), 0, stream>>>(x, Wq, Wk, pm, ls, xb, wbuf, prtF);
    proj_mfma<<<dim3(128, 8), dim3(256), 0, stream>>>(xb, wbuf, bq, bk, qf, kT);
    conv_mfma<<<dim3(32, 4), dim3(256), 0, stream>>>(prtF, kT, gpart);
    conv_combine<<<dim3(384), dim3(256), 0, stream>>>(gpart, gw);
    final_kernel<<<dim3(4096), dim3(256), 0, stream>>>(qf, gw, out);
}